// Round 8
// baseline (540.101 us; speedup 1.0000x reference)
//
#include <hip/hip_runtime.h>
#include <hip/hip_bf16.h>

typedef __attribute__((ext_vector_type(8))) short short8_t;
typedef __attribute__((ext_vector_type(4))) float floatx4;
typedef unsigned short ushort_t;
typedef unsigned int uint_t;

// ---------------- tile layout ----------------
#define TILE_B 16896    // bytes per x-row slot: 132 cols x 128 B (64 ci bf16)
// Slot content: T[col][chunk] (chunk = 8 ci = 16 B), involution swizzle:
// T[col][k] = data[col][k ^ (col & 7)]. Row r lives in slot (r & 3).

// ---------------- fallback constants ----------------
#define RSTR 72
#define TSZ  (132 * RSTR)

__device__ __forceinline__ uint_t rne_u(float f) {
    uint_t u = __float_as_uint(f);
    return u + (0x7fffu + ((u >> 16) & 1u));   // bf16(f) in bits[31:16], RNE
}
__device__ __forceinline__ uint_t pk2(float lo, float hi) {
    return __builtin_amdgcn_perm(rne_u(hi), rne_u(lo), 0x07060302u);
}

// Fused prepass. Blocks 0..4095: x (f32 NCHW) -> x2 (bf16 NHWC), one block per
// (n,h). Blocks 4096..4383: w -> w2[rd][co][c32], rd = khw*2+half.
__global__ __launch_bounds__(256)
void prepass_fused(const float* __restrict__ x, const float* __restrict__ w,
                   ushort_t* __restrict__ x2, ushort_t* __restrict__ w2)
{
    __shared__ __align__(16) float lds[64 * 129];
    const int t = threadIdx.x;
    const int b = blockIdx.x;
    if (b >= 4096) {
        int idx = (b - 4096) * 256 + t;      // 0..73727
        int rd  = idx >> 12;
        int rem = idx & 4095;
        int co  = rem >> 5;
        int c32 = rem & 31;
        int khw = rd >> 1, half = rd & 1;
        int ci  = half * 32 + c32;
        w2[idx] = (ushort_t)(rne_u(w[co * 576 + ci * 9 + khw]) >> 16);
        return;
    }
    const int n = b >> 7, h = b & 127;
    const float* xp = x + ((size_t)n << 20) + (size_t)h * 128;
#pragma unroll
    for (int r = 0; r < 16; ++r) {
        int flat = r * 256 + t;              // 0..4095
        int ci = flat >> 6, wh = flat & 63;
        float2 v = *reinterpret_cast<const float2*>(xp + (size_t)ci * 16384 + wh * 2);
        lds[ci * 129 + wh * 2]     = v.x;
        lds[ci * 129 + wh * 2 + 1] = v.y;
    }
    __syncthreads();
    ushort_t* op = x2 + ((size_t)n * 128 + h) * 8192;
#pragma unroll
    for (int r = 0; r < 4; ++r) {
        int id = r * 256 + t;                // 0..1023
        int wq = id >> 3, q = id & 7;        // w, ci-octet
        uint_t o[4];
#pragma unroll
        for (int qq = 0; qq < 4; ++qq)
            o[qq] = pk2(lds[(q * 8 + 2 * qq) * 129 + wq],
                        lds[(q * 8 + 2 * qq + 1) * 129 + wq]);
        *reinterpret_cast<uint4*>(op + (size_t)wq * 64 + q * 8) =
            make_uint4(o[0], o[1], o[2], o[3]);
    }
}

// ---------------- conv_v6: v4 sliding window, v3 per-round B loads ----------
// Block = 3 row-pairs (6 out rows) x 128 wo x 128 co; 672 blocks (8 XCD x 84);
// 512 threads = 8 waves; 2 blocks/CU. Per pair: 18 rounds; after rd11 the two
// oldest row slots are dead -> barrier + stage next 2 rows there, overlapped
// with rd12..17 MFMAs. B fragments loaded per-round (v3's proven spill-free
// body; v4's bcur/bnxt prefetch caused 416 MB of scratch spills).
__global__ __launch_bounds__(512, 4)
void conv_v6(const ushort_t* __restrict__ x2, const ushort_t* __restrict__ w2,
             const float* __restrict__ bias, float* __restrict__ out)
{
    __shared__ __align__(16) ushort_t T[4 * (TILE_B / 2)];   // 67,584 B
    __shared__ __align__(16) float red[2][256];              //  2,048 B

    const int tid  = threadIdx.x;
    const int bid0 = blockIdx.x;
    const int bid  = (bid0 & 7) * 84 + (bid0 >> 3);   // 672 = 8*84, bijective
    const int n    = bid / 21;
    const int pg   = bid - n * 21;
    const int ho0  = pg * 6;                          // 6 out rows per block

    const int lane = tid & 63;
    const int wid  = tid >> 6;          // 0..7
    const int wm   = wid >> 1;          // m-quarter
    const int wn   = wid & 1;           // co-half
    const int r16  = lane & 15;
    const int quad = lane >> 4;
    const int ms0  = wm >> 1;           // out-row within pair
    const int mc0  = (wm & 1) * 64 + r16;

    // staging lane map: col_local = lane>>3, chunk_src = (lane&7)^(lane>>3)
    const int voffB = ((lane >> 3) * 128) + (((lane & 7) ^ (lane >> 3)) * 16);
    const ushort_t* xrow = x2 + ((size_t)n * 128 + ho0) * 8192;  // 16384 B/row

    // ---- prologue: stage rows 0..3 into slots 0..3 (register-free) ----
#pragma unroll
    for (int s = 0; s < 4; ++s)
#pragma unroll
        for (int k = 0; k < 2; ++k) {
            const int col0 = (wid * 2 + k) * 8;
            const char* g = (const char*)xrow + (size_t)s * 16384 + col0 * 128 + voffB;
            const ushort_t* l = &T[(s * TILE_B + col0 * 128) / 2];
            __builtin_amdgcn_global_load_lds(
                (const __attribute__((address_space(1))) uint_t*)g,
                (__attribute__((address_space(3))) uint_t*)l, 16, 0, 0);
        }

    // zero pad cols 128..131 of all slots (never overwritten by stages)
    {
        const int s = tid >> 7, rem = tid & 127;
        reinterpret_cast<uint_t*>(T)[(s * TILE_B + (128 + (rem >> 5)) * 128) / 4 + (rem & 31)] = 0u;
    }

    floatx4 acc[4][4];
#pragma unroll
    for (int i = 0; i < 4; ++i)
#pragma unroll
        for (int j = 0; j < 4; ++j)
            acc[i][j] = (floatx4){0.f, 0.f, 0.f, 0.f};

    // B: one base, imm offsets (rd*8192 B, t4*1024 B)
    const ushort_t* w2base = w2 + (size_t)(wn * 64 + r16) * 32 + quad * 8;

    __syncthreads();   // drains prologue global_load_lds + pad writes

#pragma unroll 1
    for (int j = 0; j < 3; ++j) {
        // ---- 18 rounds for pair j (rows 2j..2j+3, slots mod 4) ----
#pragma unroll
        for (int rd = 0; rd < 18; ++rd) {
            const int khw  = rd >> 1;
            const int kh   = khw / 3;
            const int kw   = khw - kh * 3;
            const int half = rd & 1;

            // B fragments for this round (L2/L1-hot; same addrs every j)
            short8_t bfr[4];
            {
                const ushort_t* bb = w2base + rd * 4096;
#pragma unroll
                for (int t4 = 0; t4 < 4; ++t4)
                    bfr[t4] = *reinterpret_cast<const short8_t*>(bb + t4 * 512);
            }

            short8_t afr[4];
            {
                const int sl = (2 * j + kh + ms0) & 3;   // slot of row 2j+kh+ms0
                const int c0 = mc0 + kw;
                const int abase = sl * TILE_B + c0 * 128
                                + (((half * 4 + quad) ^ (c0 & 7)) * 16);
                const char* ap = (const char*)T + abase;
#pragma unroll
                for (int t4 = 0; t4 < 4; ++t4)
                    afr[t4] = *reinterpret_cast<const short8_t*>(ap + t4 * 2048);
            }
#pragma unroll
            for (int tm = 0; tm < 4; ++tm)
#pragma unroll
                for (int tn = 0; tn < 4; ++tn)
                    acc[tm][tn] = __builtin_amdgcn_mfma_f32_16x16x32_bf16(
                        afr[tm], bfr[tn], acc[tm][tn], 0, 0, 0);

            if (rd == 11) {
                // rows 2j, 2j+1 (slots (2j)&3, (2j+1)&3) are dead: rd12..17
                // (kh=2) only touch slots (2j+2)&3, (2j+3)&3.
                __syncthreads();
                if (j < 2) {
                    const int lr = 2 * j + 4;   // global rows ho0+lr, ho0+lr+1
#pragma unroll
                    for (int rr = 0; rr < 2; ++rr)
#pragma unroll
                        for (int k = 0; k < 2; ++k) {
                            const int col0 = (wid * 2 + k) * 8;
                            const char* g = (const char*)xrow
                                + (size_t)(lr + rr) * 16384 + col0 * 128 + voffB;
                            const ushort_t* l =
                                &T[(((lr + rr) & 3) * TILE_B + col0 * 128) / 2];
                            __builtin_amdgcn_global_load_lds(
                                (const __attribute__((address_space(1))) uint_t*)g,
                                (__attribute__((address_space(3))) uint_t*)l, 16, 0, 0);
                        }
                    // first READ of these slots is pair j+1 rd6; the epilogue
                    // __syncthreads (vmcnt(0) drain) orders it.
                }
            }
        }

        // ---- epilogue pair j: +bias, min over co, cross-lane min, tanh ----
        float bvv[4];
#pragma unroll
        for (int tn = 0; tn < 4; ++tn)
            bvv[tn] = bias[wn * 64 + tn * 16 + r16];

#pragma unroll
        for (int tm = 0; tm < 4; ++tm) {
#pragma unroll
            for (int r = 0; r < 4; ++r) {
                float v = acc[tm][0][r] + bvv[0];
                v = fminf(v, acc[tm][1][r] + bvv[1]);
                v = fminf(v, acc[tm][2][r] + bvv[2]);
                v = fminf(v, acc[tm][3][r] + bvv[3]);
                v = fminf(v, __shfl_xor(v, 1, 64));
                v = fminf(v, __shfl_xor(v, 2, 64));
                v = fminf(v, __shfl_xor(v, 4, 64));
                v = fminf(v, __shfl_xor(v, 8, 64));
                if (r16 == 0)
                    red[wn][wm * 64 + tm * 16 + quad * 4 + r] = v;
            }
        }
        __syncthreads();   // also drains the rd11 stage (vmcnt(0))

        if (tid < 256) {
            const int r  = tid >> 7;
            const int wo = tid & 127;
            if (wo < 126) {
                float v = fminf(red[0][tid], red[1][tid]);
                v = tanhf(tanhf(v));
                out[((size_t)n * 126 + ho0 + 2 * j + r) * 126 + wo] = v;
            }
        }

        // reset accumulator for next pair
#pragma unroll
        for (int i = 0; i < 4; ++i)
#pragma unroll
            for (int k = 0; k < 4; ++k)
                acc[i][k] = (floatx4){0.f, 0.f, 0.f, 0.f};
    }
}

// ---------------- fallback (proven r2 path): register-staged f32 ----------
__global__ void w2_prepass(const float* __restrict__ w, ushort_t* __restrict__ w2) {
    int idx = blockIdx.x * 256 + threadIdx.x;  // 73728
    int rd  = idx >> 12;
    int rem = idx & 4095;
    int co  = rem >> 5;
    int c32 = rem & 31;
    int khw = rd >> 1, half = rd & 1;
    int ci  = half * 32 + c32;
    w2[idx] = (ushort_t)(rne_u(w[co * 576 + ci * 9 + khw]) >> 16);
}

template<bool USE_W2>
__global__ __launch_bounds__(512, 4)
void conv_min_tanh_kernel(const float* __restrict__ x,
                          const float* __restrict__ w,
                          const ushort_t* __restrict__ w2,
                          const float* __restrict__ bias,
                          float* __restrict__ out)
{
    __shared__ __align__(16) ushort_t T[4 * TSZ];
    __shared__ __align__(16) float red[2][256];

    const int tid  = threadIdx.x;
    const int bid0 = blockIdx.x;
    const int bid  = (bid0 & 7) * 252 + (bid0 >> 3);
    const int n    = bid / 63;
    const int ho0  = (bid - n * 63) * 2;

    const int tx = tid & 31;
    const int ty = tid >> 5;

    const int lane = tid & 63;
    const int wid  = tid >> 6;
    const int wm   = wid >> 1;
    const int wn   = wid & 1;
    const int r16  = lane & 15;
    const int quad = lane >> 4;

    const float* xbase = x + ((size_t)n << 20) + (size_t)ho0 * 128;

    auto load_row = [&](floatx4 (&dv)[4], const int s) {
#pragma unroll
        for (int j = 0; j < 4; ++j)
            dv[j] = *reinterpret_cast<const floatx4*>(
                xbase + (size_t)(ty * 4 + j) * 16384 + s * 128 + tx * 4);
    };
    auto conv_row = [&](floatx4 (&dv)[4], const int s) {
#pragma unroll
        for (int i = 0; i < 4; ++i) {
            uint2 u;
            u.x = pk2(dv[0][i], dv[1][i]);
            u.y = pk2(dv[2][i], dv[3][i]);
            const int c   = tx * 4 + i;
            const int swz = (ty >> 1) ^ ((c >> 3) & 7);
            *reinterpret_cast<uint2*>(&T[s * TSZ + c * RSTR + swz * 8 + (ty & 1) * 4]) = u;
        }
    };

    floatx4 dva[4], dvb[4];
    load_row(dva, 0);
    load_row(dvb, 1);

    for (int idx = tid; idx < 576; idx += 512) {
        int s = idx / 144, o = idx - s * 144;
        reinterpret_cast<uint_t*>(T)[s * (TSZ / 2) + (128 * RSTR) / 2 + o] = 0u;
    }

    conv_row(dva, 0);
    load_row(dva, 2);
    conv_row(dvb, 1);
    load_row(dvb, 3);
    conv_row(dva, 2);
    conv_row(dvb, 3);

    floatx4 acc[4][4];
#pragma unroll
    for (int i = 0; i < 4; ++i)
#pragma unroll
        for (int j = 0; j < 4; ++j)
            acc[i][j] = (floatx4){0.f, 0.f, 0.f, 0.f};

    const ushort_t* w2base = w2 + (size_t)(wn * 64 + r16) * 32 + quad * 8;
    const float*    wbase  = w + (size_t)(wn * 64 + r16) * 576;

    __syncthreads();

#pragma unroll
    for (int rd = 0; rd < 18; ++rd) {
        const int khw  = rd >> 1;
        const int kh   = khw / 3;
        const int kw   = khw - kh * 3;
        const int half = rd & 1;

        short8_t bfr[4];
        if (USE_W2) {
            const ushort_t* bb = w2base + rd * 4096;
#pragma unroll
            for (int t4 = 0; t4 < 4; ++t4)
                bfr[t4] = *reinterpret_cast<const short8_t*>(bb + t4 * 512);
        } else {
#pragma unroll
            for (int t4 = 0; t4 < 4; ++t4) {
                const float* wp = wbase + (size_t)t4 * (16 * 576)
                                + (size_t)(half * 32 + quad * 8) * 9 + khw;
                short8_t b;
#pragma unroll
                for (int q = 0; q < 4; ++q) {
                    uint_t u = pk2(wp[(2 * q) * 9], wp[(2 * q + 1) * 9]);
                    b[2 * q]     = (short)(u & 0xffffu);
                    b[2 * q + 1] = (short)(u >> 16);
                }
                bfr[t4] = b;
            }
        }

        short8_t afr[4];
#pragma unroll
        for (int t4 = 0; t4 < 4; ++t4) {
            const int m  = wm * 64 + t4 * 16 + r16;
            const int s  = (m >> 7) + kh;
            const int c  = (m & 127) + kw;
            const int sw = (half * 4 + quad) ^ ((c >> 3) & 7);
            afr[t4] = *reinterpret_cast<const short8_t*>(&T[s * TSZ + c * RSTR + sw * 8]);
        }
#pragma unroll
        for (int tm = 0; tm < 4; ++tm)
#pragma unroll
            for (int tn = 0; tn < 4; ++tn)
                acc[tm][tn] = __builtin_amdgcn_mfma_f32_16x16x32_bf16(
                    afr[tm], bfr[tn], acc[tm][tn], 0, 0, 0);
    }

    float bvv[4];
#pragma unroll
    for (int tn = 0; tn < 4; ++tn)
        bvv[tn] = bias[wn * 64 + tn * 16 + r16];

#pragma unroll
    for (int tm = 0; tm < 4; ++tm) {
#pragma unroll
        for (int r = 0; r < 4; ++r) {
            float v = acc[tm][0][r] + bvv[0];
            v = fminf(v, acc[tm][1][r] + bvv[1]);
            v = fminf(v, acc[tm][2][r] + bvv[2]);
            v = fminf(v, acc[tm][3][r] + bvv[3]);
            v = fminf(v, __shfl_xor(v, 1, 64));
            v = fminf(v, __shfl_xor(v, 2, 64));
            v = fminf(v, __shfl_xor(v, 4, 64));
            v = fminf(v, __shfl_xor(v, 8, 64));
            if (r16 == 0)
                red[wn][wm * 64 + tm * 16 + quad * 4 + r] = v;
        }
    }
    __syncthreads();

    if (tid < 256) {
        const int r  = tid >> 7;
        const int wo = tid & 127;
        if (wo < 126) {
            float v = fminf(red[0][tid], red[1][tid]);
            v = tanhf(tanhf(v));
            out[((size_t)n * 126 + ho0 + r) * 126 + wo] = v;
        }
    }
}

extern "C" void kernel_launch(void* const* d_in, const int* in_sizes, int n_in,
                              void* d_out, int out_size, void* d_ws, size_t ws_size,
                              hipStream_t stream) {
    const float* x    = (const float*)d_in[0];   // [32,64,128,128] f32
    const float* w    = (const float*)d_in[1];   // [128,64,3,3] f32
    const float* bias = (const float*)d_in[2];   // [128] f32
    float* out = (float*)d_out;                  // [32,1,126,126] f32

    const size_t X2B = (size_t)32 * 128 * 128 * 64 * 2;   // 67,108,864 B
    const size_t W2B = (size_t)73728 * 2;                 // 147,456 B

    if (ws_size >= X2B + W2B) {
        ushort_t* x2 = (ushort_t*)d_ws;
        ushort_t* w2 = (ushort_t*)((char*)d_ws + X2B);
        prepass_fused<<<dim3(4096 + 288), dim3(256), 0, stream>>>(x, w, x2, w2);
        conv_v6<<<dim3(672), dim3(512), 0, stream>>>(x2, w2, bias, out);
    } else if (ws_size >= W2B) {
        ushort_t* w2 = (ushort_t*)d_ws;
        w2_prepass<<<dim3(288), dim3(256), 0, stream>>>(w, w2);
        conv_min_tanh_kernel<true><<<dim3(2016), dim3(512), 0, stream>>>(x, w, w2, bias, out);
    } else {
        conv_min_tanh_kernel<false><<<dim3(2016), dim3(512), 0, stream>>>(x, w, nullptr, bias, out);
    }
}

// Round 9
// 276.259 us; speedup vs baseline: 1.9551x; 1.9551x over previous
//
#include <hip/hip_runtime.h>
#include <hip/hip_bf16.h>

typedef __attribute__((ext_vector_type(8))) short short8_t;
typedef __attribute__((ext_vector_type(4))) float floatx4;
typedef unsigned short ushort_t;
typedef unsigned int uint_t;

// ---------------- tile layout ----------------
#define TILE_B 16896    // bytes per x-row slot: 132 cols x 128 B (64 ci bf16)
// Slot content: T[col][chunk] (chunk = 8 ci = 16 B), involution swizzle:
// T[col][k] = data[col][k ^ (col & 7)].

// ---------------- fallback constants ----------------
#define RSTR 72
#define TSZ  (132 * RSTR)

__device__ __forceinline__ uint_t rne_u(float f) {
    uint_t u = __float_as_uint(f);
    return u + (0x7fffu + ((u >> 16) & 1u));   // bf16(f) in bits[31:16], RNE
}
__device__ __forceinline__ uint_t pk2(float lo, float hi) {
    return __builtin_amdgcn_perm(rne_u(hi), rne_u(lo), 0x07060302u);
}

// Fused prepass. Blocks 0..4095: x (f32 NCHW) -> x2 (bf16 NHWC), one block per
// (n,h). Blocks 4096..4383: w -> w2[rd][co][c32], rd = khw*2+half.
__global__ __launch_bounds__(256)
void prepass_fused(const float* __restrict__ x, const float* __restrict__ w,
                   ushort_t* __restrict__ x2, ushort_t* __restrict__ w2)
{
    __shared__ __align__(16) float lds[64 * 129];
    const int t = threadIdx.x;
    const int b = blockIdx.x;
    if (b >= 4096) {
        int idx = (b - 4096) * 256 + t;      // 0..73727
        int rd  = idx >> 12;
        int rem = idx & 4095;
        int co  = rem >> 5;
        int c32 = rem & 31;
        int khw = rd >> 1, half = rd & 1;
        int ci  = half * 32 + c32;
        w2[idx] = (ushort_t)(rne_u(w[co * 576 + ci * 9 + khw]) >> 16);
        return;
    }
    const int n = b >> 7, h = b & 127;
    const float* xp = x + ((size_t)n << 20) + (size_t)h * 128;
#pragma unroll
    for (int r = 0; r < 16; ++r) {
        int flat = r * 256 + t;              // 0..4095
        int ci = flat >> 6, wh = flat & 63;
        float2 v = *reinterpret_cast<const float2*>(xp + (size_t)ci * 16384 + wh * 2);
        lds[ci * 129 + wh * 2]     = v.x;
        lds[ci * 129 + wh * 2 + 1] = v.y;
    }
    __syncthreads();
    ushort_t* op = x2 + ((size_t)n * 128 + h) * 8192;
#pragma unroll
    for (int r = 0; r < 4; ++r) {
        int id = r * 256 + t;                // 0..1023
        int wq = id >> 3, q = id & 7;        // w, ci-octet
        uint_t o[4];
#pragma unroll
        for (int qq = 0; qq < 4; ++qq)
            o[qq] = pk2(lds[(q * 8 + 2 * qq) * 129 + wq],
                        lds[(q * 8 + 2 * qq + 1) * 129 + wq]);
        *reinterpret_cast<uint4*>(op + (size_t)wq * 64 + q * 8) =
            make_uint4(o[0], o[1], o[2], o[3]);
    }
}

// ---------------- conv_v7: v3 geometry + explicit 2-deep B pipeline ---------
// Block = 2 out rows x 128 wo x 128 co, 512 threads = 8 waves, 2 blocks/CU.
// Straight-line 18 rounds (NO runtime loop around the rounds: a runtime loop
// lets LICM hoist all 72 B-loads and spill ~390 MB — v4/v6 post-mortem).
// Round rd's B fragments are loaded during round rd-1 (bnxt), hiding the
// ~300-cycle L2 latency that the v3-vs-v5 A/B identified as the per-round
// fixed cost. Staging is register-free (global_load_lds) so the pipeline
// fits the 64-arch-VGPR budget: acc 64 AGPR + bcur16 + bnxt16 + afr16 + addr.
__global__ __launch_bounds__(512, 4)
void conv_v7(const ushort_t* __restrict__ x2, const ushort_t* __restrict__ w2,
             const float* __restrict__ bias, float* __restrict__ out)
{
    __shared__ __align__(16) ushort_t T[4 * (TILE_B / 2)];   // 67,584 B
    __shared__ __align__(16) float red[2][256];              //  2,048 B

    const int tid  = threadIdx.x;
    // XCD swizzle: 2016 = 8 x 252 -> contiguous row-pair runs per XCD L2
    const int bid0 = blockIdx.x;
    const int bid  = (bid0 & 7) * 252 + (bid0 >> 3);
    const int n    = bid / 63;
    const int ho0  = (bid - n * 63) * 2;

    const int lane = tid & 63;
    const int wid  = tid >> 6;          // 0..7
    const int wm   = wid >> 1;          // m-quarter
    const int wn   = wid & 1;           // co-half
    const int r16  = lane & 15;
    const int quad = lane >> 4;

    // ---- register-free staging: 4 slots x 2 insts ----
    const int voffB = ((lane >> 3) * 128) + (((lane & 7) ^ (lane >> 3)) * 16);
    const ushort_t* xrow = x2 + ((size_t)n * 128 + ho0) * 8192;  // 16384 B/row
#pragma unroll
    for (int s = 0; s < 4; ++s)
#pragma unroll
        for (int k = 0; k < 2; ++k) {
            const int col0 = (wid * 2 + k) * 8;
            const char* g = (const char*)xrow + (size_t)s * 16384 + col0 * 128 + voffB;
            const ushort_t* l = &T[(s * TILE_B + col0 * 128) / 2];
            __builtin_amdgcn_global_load_lds(
                (const __attribute__((address_space(1))) uint_t*)g,
                (__attribute__((address_space(3))) uint_t*)l, 16, 0, 0);
        }

    // zero pad cols 128..131
    {
        const int s = tid >> 7, rem = tid & 127;
        reinterpret_cast<uint_t*>(T)[(s * TILE_B + (128 + (rem >> 5)) * 128) / 4 + (rem & 31)] = 0u;
    }

    floatx4 acc[4][4];
#pragma unroll
    for (int i = 0; i < 4; ++i)
#pragma unroll
        for (int j = 0; j < 4; ++j)
            acc[i][j] = (floatx4){0.f, 0.f, 0.f, 0.f};

    // B: one base, imm offsets (rd*8192 B, t4*1024 B)
    const ushort_t* w2base = w2 + (size_t)(wn * 64 + r16) * 32 + quad * 8;

    const int mc0 = (wm & 1) * 64 + r16;
    const int ms0 = wm >> 1;

    // preload round 0's B while the stage drains
    short8_t bcur[4], bnxt[4];
#pragma unroll
    for (int t4 = 0; t4 < 4; ++t4)
        bcur[t4] = *reinterpret_cast<const short8_t*>(w2base + t4 * 512);

    __syncthreads();   // drains global_load_lds + pad writes

    // ---- 18 straight-line rounds: kh x kw x ci-half, K=32 each ----
#pragma unroll
    for (int rd = 0; rd < 18; ++rd) {
        // issue next round's B first: a full round of MFMA issue covers L2 lat
        if (rd < 17) {
            const ushort_t* bb = w2base + (rd + 1) * 4096;
#pragma unroll
            for (int t4 = 0; t4 < 4; ++t4)
                bnxt[t4] = *reinterpret_cast<const short8_t*>(bb + t4 * 512);
        }

        const int khw  = rd >> 1;
        const int kh   = khw / 3;
        const int kw   = khw - kh * 3;
        const int half = rd & 1;

        short8_t afr[4];
        {
            const int c0 = mc0 + kw;
            const int abase = (ms0 + kh) * TILE_B + c0 * 128
                            + (((half * 4 + quad) ^ (c0 & 7)) * 16);
            const char* ap = (const char*)T + abase;
#pragma unroll
            for (int t4 = 0; t4 < 4; ++t4)
                afr[t4] = *reinterpret_cast<const short8_t*>(ap + t4 * 2048);
        }

#pragma unroll
        for (int tm = 0; tm < 4; ++tm)
#pragma unroll
            for (int tn = 0; tn < 4; ++tn)
                acc[tm][tn] = __builtin_amdgcn_mfma_f32_16x16x32_bf16(
                    afr[tm], bcur[tn], acc[tm][tn], 0, 0, 0);

#pragma unroll
        for (int t4 = 0; t4 < 4; ++t4)   // SSA rotation; free after full unroll
            bcur[t4] = bnxt[t4];
    }

    // ---- epilogue: +bias, min over co, cross-lane min, tanh(tanh) ----
    float bvv[4];
#pragma unroll
    for (int tn = 0; tn < 4; ++tn)
        bvv[tn] = bias[wn * 64 + tn * 16 + r16];

#pragma unroll
    for (int tm = 0; tm < 4; ++tm) {
#pragma unroll
        for (int r = 0; r < 4; ++r) {
            float v = acc[tm][0][r] + bvv[0];
            v = fminf(v, acc[tm][1][r] + bvv[1]);
            v = fminf(v, acc[tm][2][r] + bvv[2]);
            v = fminf(v, acc[tm][3][r] + bvv[3]);
            v = fminf(v, __shfl_xor(v, 1, 64));
            v = fminf(v, __shfl_xor(v, 2, 64));
            v = fminf(v, __shfl_xor(v, 4, 64));
            v = fminf(v, __shfl_xor(v, 8, 64));
            if (r16 == 0)
                red[wn][wm * 64 + tm * 16 + quad * 4 + r] = v;
        }
    }
    __syncthreads();

    if (tid < 256) {
        const int r  = tid >> 7;
        const int wo = tid & 127;
        if (wo < 126) {
            float v = fminf(red[0][tid], red[1][tid]);
            v = tanhf(tanhf(v));
            out[((size_t)n * 126 + ho0 + r) * 126 + wo] = v;
        }
    }
}

// ---------------- fallback (proven r2 path): register-staged f32 ----------
__global__ void w2_prepass(const float* __restrict__ w, ushort_t* __restrict__ w2) {
    int idx = blockIdx.x * 256 + threadIdx.x;  // 73728
    int rd  = idx >> 12;
    int rem = idx & 4095;
    int co  = rem >> 5;
    int c32 = rem & 31;
    int khw = rd >> 1, half = rd & 1;
    int ci  = half * 32 + c32;
    w2[idx] = (ushort_t)(rne_u(w[co * 576 + ci * 9 + khw]) >> 16);
}

template<bool USE_W2>
__global__ __launch_bounds__(512, 4)
void conv_min_tanh_kernel(const float* __restrict__ x,
                          const float* __restrict__ w,
                          const ushort_t* __restrict__ w2,
                          const float* __restrict__ bias,
                          float* __restrict__ out)
{
    __shared__ __align__(16) ushort_t T[4 * TSZ];
    __shared__ __align__(16) float red[2][256];

    const int tid  = threadIdx.x;
    const int bid0 = blockIdx.x;
    const int bid  = (bid0 & 7) * 252 + (bid0 >> 3);
    const int n    = bid / 63;
    const int ho0  = (bid - n * 63) * 2;

    const int tx = tid & 31;
    const int ty = tid >> 5;

    const int lane = tid & 63;
    const int wid  = tid >> 6;
    const int wm   = wid >> 1;
    const int wn   = wid & 1;
    const int r16  = lane & 15;
    const int quad = lane >> 4;

    const float* xbase = x + ((size_t)n << 20) + (size_t)ho0 * 128;

    auto load_row = [&](floatx4 (&dv)[4], const int s) {
#pragma unroll
        for (int j = 0; j < 4; ++j)
            dv[j] = *reinterpret_cast<const floatx4*>(
                xbase + (size_t)(ty * 4 + j) * 16384 + s * 128 + tx * 4);
    };
    auto conv_row = [&](floatx4 (&dv)[4], const int s) {
#pragma unroll
        for (int i = 0; i < 4; ++i) {
            uint2 u;
            u.x = pk2(dv[0][i], dv[1][i]);
            u.y = pk2(dv[2][i], dv[3][i]);
            const int c   = tx * 4 + i;
            const int swz = (ty >> 1) ^ ((c >> 3) & 7);
            *reinterpret_cast<uint2*>(&T[s * TSZ + c * RSTR + swz * 8 + (ty & 1) * 4]) = u;
        }
    };

    floatx4 dva[4], dvb[4];
    load_row(dva, 0);
    load_row(dvb, 1);

    for (int idx = tid; idx < 576; idx += 512) {
        int s = idx / 144, o = idx - s * 144;
        reinterpret_cast<uint_t*>(T)[s * (TSZ / 2) + (128 * RSTR) / 2 + o] = 0u;
    }

    conv_row(dva, 0);
    load_row(dva, 2);
    conv_row(dvb, 1);
    load_row(dvb, 3);
    conv_row(dva, 2);
    conv_row(dvb, 3);

    floatx4 acc[4][4];
#pragma unroll
    for (int i = 0; i < 4; ++i)
#pragma unroll
        for (int j = 0; j < 4; ++j)
            acc[i][j] = (floatx4){0.f, 0.f, 0.f, 0.f};

    const ushort_t* w2base = w2 + (size_t)(wn * 64 + r16) * 32 + quad * 8;
    const float*    wbase  = w + (size_t)(wn * 64 + r16) * 576;

    __syncthreads();

#pragma unroll
    for (int rd = 0; rd < 18; ++rd) {
        const int khw  = rd >> 1;
        const int kh   = khw / 3;
        const int kw   = khw - kh * 3;
        const int half = rd & 1;

        short8_t bfr[4];
        if (USE_W2) {
            const ushort_t* bb = w2base + rd * 4096;
#pragma unroll
            for (int t4 = 0; t4 < 4; ++t4)
                bfr[t4] = *reinterpret_cast<const short8_t*>(bb + t4 * 512);
        } else {
#pragma unroll
            for (int t4 = 0; t4 < 4; ++t4) {
                const float* wp = wbase + (size_t)t4 * (16 * 576)
                                + (size_t)(half * 32 + quad * 8) * 9 + khw;
                short8_t b;
#pragma unroll
                for (int q = 0; q < 4; ++q) {
                    uint_t u = pk2(wp[(2 * q) * 9], wp[(2 * q + 1) * 9]);
                    b[2 * q]     = (short)(u & 0xffffu);
                    b[2 * q + 1] = (short)(u >> 16);
                }
                bfr[t4] = b;
            }
        }

        short8_t afr[4];
#pragma unroll
        for (int t4 = 0; t4 < 4; ++t4) {
            const int m  = wm * 64 + t4 * 16 + r16;
            const int s  = (m >> 7) + kh;
            const int c  = (m & 127) + kw;
            const int sw = (half * 4 + quad) ^ ((c >> 3) & 7);
            afr[t4] = *reinterpret_cast<const short8_t*>(&T[s * TSZ + c * RSTR + sw * 8]);
        }
#pragma unroll
        for (int tm = 0; tm < 4; ++tm)
#pragma unroll
            for (int tn = 0; tn < 4; ++tn)
                acc[tm][tn] = __builtin_amdgcn_mfma_f32_16x16x32_bf16(
                    afr[tm], bfr[tn], acc[tm][tn], 0, 0, 0);
    }

    float bvv[4];
#pragma unroll
    for (int tn = 0; tn < 4; ++tn)
        bvv[tn] = bias[wn * 64 + tn * 16 + r16];

#pragma unroll
    for (int tm = 0; tm < 4; ++tm) {
#pragma unroll
        for (int r = 0; r < 4; ++r) {
            float v = acc[tm][0][r] + bvv[0];
            v = fminf(v, acc[tm][1][r] + bvv[1]);
            v = fminf(v, acc[tm][2][r] + bvv[2]);
            v = fminf(v, acc[tm][3][r] + bvv[3]);
            v = fminf(v, __shfl_xor(v, 1, 64));
            v = fminf(v, __shfl_xor(v, 2, 64));
            v = fminf(v, __shfl_xor(v, 4, 64));
            v = fminf(v, __shfl_xor(v, 8, 64));
            if (r16 == 0)
                red[wn][wm * 64 + tm * 16 + quad * 4 + r] = v;
        }
    }
    __syncthreads();

    if (tid < 256) {
        const int r  = tid >> 7;
        const int wo = tid & 127;
        if (wo < 126) {
            float v = fminf(red[0][tid], red[1][tid]);
            v = tanhf(tanhf(v));
            out[((size_t)n * 126 + ho0 + r) * 126 + wo] = v;
        }
    }
}

extern "C" void kernel_launch(void* const* d_in, const int* in_sizes, int n_in,
                              void* d_out, int out_size, void* d_ws, size_t ws_size,
                              hipStream_t stream) {
    const float* x    = (const float*)d_in[0];   // [32,64,128,128] f32
    const float* w    = (const float*)d_in[1];   // [128,64,3,3] f32
    const float* bias = (const float*)d_in[2];   // [128] f32
    float* out = (float*)d_out;                  // [32,1,126,126] f32

    const size_t X2B = (size_t)32 * 128 * 128 * 64 * 2;   // 67,108,864 B
    const size_t W2B = (size_t)73728 * 2;                 // 147,456 B

    if (ws_size >= X2B + W2B) {
        ushort_t* x2 = (ushort_t*)d_ws;
        ushort_t* w2 = (ushort_t*)((char*)d_ws + X2B);
        prepass_fused<<<dim3(4096 + 288), dim3(256), 0, stream>>>(x, w, x2, w2);
        conv_v7<<<dim3(2016), dim3(512), 0, stream>>>(x2, w2, bias, out);
    } else if (ws_size >= W2B) {
        ushort_t* w2 = (ushort_t*)d_ws;
        w2_prepass<<<dim3(288), dim3(256), 0, stream>>>(w, w2);
        conv_min_tanh_kernel<true><<<dim3(2016), dim3(512), 0, stream>>>(x, w, w2, bias, out);
    } else {
        conv_min_tanh_kernel<false><<<dim3(2016), dim3(512), 0, stream>>>(x, w, nullptr, bias, out);
    }
}

// Round 10
// 268.906 us; speedup vs baseline: 2.0085x; 1.0273x over previous
//
#include <hip/hip_runtime.h>
#include <hip/hip_bf16.h>

typedef __attribute__((ext_vector_type(8))) short short8_t;
typedef __attribute__((ext_vector_type(4))) float floatx4;
typedef unsigned short ushort_t;
typedef unsigned int uint_t;

// ---------------- tile layout ----------------
#define TILE_B 16896    // bytes per x-row slot: 132 cols x 128 B (64 ci bf16)
// Slot content: T[col][chunk] (chunk = 8 ci = 16 B), involution swizzle:
// T[col][k] = data[col][k ^ (col & 7)].

// ---------------- fallback constants ----------------
#define RSTR 72
#define TSZ  (132 * RSTR)

__device__ __forceinline__ uint_t rne_u(float f) {
    uint_t u = __float_as_uint(f);
    return u + (0x7fffu + ((u >> 16) & 1u));   // bf16(f) in bits[31:16], RNE
}
__device__ __forceinline__ uint_t pk2(float lo, float hi) {
    return __builtin_amdgcn_perm(rne_u(hi), rne_u(lo), 0x07060302u);
}

// Fused prepass. Blocks 0..4095: x (f32 NCHW) -> x2 (bf16 NHWC), one block per
// (n,h), float4 loads + LDS transpose + 16B stores.
// Blocks 4096..4383: w -> w2[rd][co][c32], rd = khw*2+half.
__global__ __launch_bounds__(256)
void prepass_fused(const float* __restrict__ x, const float* __restrict__ w,
                   ushort_t* __restrict__ x2, ushort_t* __restrict__ w2)
{
    __shared__ __align__(16) float lds[64 * 129];
    const int t = threadIdx.x;
    const int b = blockIdx.x;
    if (b >= 4096) {
        int idx = (b - 4096) * 256 + t;      // 0..73727
        int rd  = idx >> 12;
        int rem = idx & 4095;
        int co  = rem >> 5;
        int c32 = rem & 31;
        int khw = rd >> 1, half = rd & 1;
        int ci  = half * 32 + c32;
        w2[idx] = (ushort_t)(rne_u(w[co * 576 + ci * 9 + khw]) >> 16);
        return;
    }
    const int n = b >> 7, h = b & 127;
    const float* xp = x + ((size_t)n << 20) + (size_t)h * 128;
#pragma unroll
    for (int r = 0; r < 8; ++r) {
        int flat = r * 256 + t;              // 0..2047
        int ci = flat >> 5, wq = flat & 31;  // ci, 4-float w group
        float4 v = *reinterpret_cast<const float4*>(xp + (size_t)ci * 16384 + wq * 4);
        lds[ci * 129 + wq * 4 + 0] = v.x;
        lds[ci * 129 + wq * 4 + 1] = v.y;
        lds[ci * 129 + wq * 4 + 2] = v.z;
        lds[ci * 129 + wq * 4 + 3] = v.w;
    }
    __syncthreads();
    ushort_t* op = x2 + ((size_t)n * 128 + h) * 8192;
#pragma unroll
    for (int r = 0; r < 4; ++r) {
        int id = r * 256 + t;                // 0..1023
        int wq = id >> 3, q = id & 7;        // w, ci-octet
        uint_t o[4];
#pragma unroll
        for (int qq = 0; qq < 4; ++qq)
            o[qq] = pk2(lds[(q * 8 + 2 * qq) * 129 + wq],
                        lds[(q * 8 + 2 * qq + 1) * 129 + wq]);
        *reinterpret_cast<uint4*>(op + (size_t)wq * 64 + q * 8) =
            make_uint4(o[0], o[1], o[2], o[3]);
    }
}

// ---------------- conv_v8: tm=8 wave tile (128x64), 256-reg waves ------------
// Block = 2 out rows x 128 wo x 128 co, 256 threads = 4 waves (wm=out-row,
// wn=co-half); wave tile M=128 N=64 -> acc[8][4] = 128 AGPR at
// __launch_bounds__(256,2) = 256 unified regs. Each B fragment now feeds 8
// MFMAs (was 4): per-CU B-load instructions halve (the co-limiting VMEM cost
// identified in r9's post-mortem). 18 straight-line rounds (no runtime loop
// = no LICM spill hazard), register-free staging, 2-deep B pipeline.
__global__ __launch_bounds__(256, 2)
void conv_v8(const ushort_t* __restrict__ x2, const ushort_t* __restrict__ w2,
             const float* __restrict__ bias, float* __restrict__ out)
{
    __shared__ __align__(16) ushort_t T[4 * (TILE_B / 2)];   // 67,584 B
    __shared__ __align__(16) float red[2][256];              //  2,048 B

    const int tid  = threadIdx.x;
    // XCD swizzle: 2016 = 8 x 252 -> contiguous row-pair runs per XCD L2
    const int bid0 = blockIdx.x;
    const int bid  = (bid0 & 7) * 252 + (bid0 >> 3);
    const int n    = bid / 63;
    const int ho0  = (bid - n * 63) * 2;

    const int lane = tid & 63;
    const int wid  = tid >> 6;          // 0..3
    const int wm   = wid >> 1;          // out-row within pair (0..1)
    const int wn   = wid & 1;           // co-half
    const int r16  = lane & 15;
    const int quad = lane >> 4;

    // ---- register-free staging: 4 slots x 4 insts/thread ----
    const int voffB = ((lane >> 3) * 128) + (((lane & 7) ^ (lane >> 3)) * 16);
    const ushort_t* xrow = x2 + ((size_t)n * 128 + ho0) * 8192;  // 16384 B/row
#pragma unroll
    for (int s = 0; s < 4; ++s)
#pragma unroll
        for (int k = 0; k < 4; ++k) {
            const int col0 = (wid * 4 + k) * 8;            // 0..120
            const char* g = (const char*)xrow + (size_t)s * 16384 + col0 * 128 + voffB;
            const ushort_t* l = &T[(s * TILE_B + col0 * 128) / 2];
            __builtin_amdgcn_global_load_lds(
                (const __attribute__((address_space(1))) uint_t*)g,
                (__attribute__((address_space(3))) uint_t*)l, 16, 0, 0);
        }

    // zero pad cols 128..131 of all 4 slots (512 uints, 2 iters)
#pragma unroll
    for (int it = 0; it < 2; ++it) {
        const int idx = it * 256 + tid;
        const int s = idx >> 7, rem = idx & 127;
        reinterpret_cast<uint_t*>(T)[(s * TILE_B + (128 + (rem >> 5)) * 128) / 4 + (rem & 31)] = 0u;
    }

    floatx4 acc[8][4];
#pragma unroll
    for (int i = 0; i < 8; ++i)
#pragma unroll
        for (int j = 0; j < 4; ++j)
            acc[i][j] = (floatx4){0.f, 0.f, 0.f, 0.f};

    // B: one base, imm offsets (rd*8192 B, tn*1024 B)
    const ushort_t* w2base = w2 + (size_t)(wn * 64 + r16) * 32 + quad * 8;

    // preload round 0's B while the stage drains
    short8_t bcur[4], bnxt[4];
#pragma unroll
    for (int tn = 0; tn < 4; ++tn)
        bcur[tn] = *reinterpret_cast<const short8_t*>(w2base + tn * 512);

    __syncthreads();   // drains global_load_lds + pad writes

    // ---- 18 straight-line rounds: kh x kw x ci-half, K=32 each ----
#pragma unroll
    for (int rd = 0; rd < 18; ++rd) {
        if (rd < 17) {
            const ushort_t* bb = w2base + (rd + 1) * 4096;
#pragma unroll
            for (int tn = 0; tn < 4; ++tn)
                bnxt[tn] = *reinterpret_cast<const short8_t*>(bb + tn * 512);
        }

        const int khw  = rd >> 1;
        const int kh   = khw / 3;
        const int kw   = khw - kh * 3;
        const int half = rd & 1;

        // A: m = wm*128 + tm*16 + r16 -> out-row wm, wo = tm*16 + r16
        short8_t afr[8];
        {
            const int c0 = r16 + kw;
            const int abase = (wm + kh) * TILE_B + c0 * 128
                            + (((half * 4 + quad) ^ (c0 & 7)) * 16);
            const char* ap = (const char*)T + abase;
#pragma unroll
            for (int tm = 0; tm < 8; ++tm)
                afr[tm] = *reinterpret_cast<const short8_t*>(ap + tm * 2048);
        }

#pragma unroll
        for (int tm = 0; tm < 8; ++tm)
#pragma unroll
            for (int tn = 0; tn < 4; ++tn)
                acc[tm][tn] = __builtin_amdgcn_mfma_f32_16x16x32_bf16(
                    afr[tm], bcur[tn], acc[tm][tn], 0, 0, 0);

#pragma unroll
        for (int tn = 0; tn < 4; ++tn)   // SSA rotation; free after full unroll
            bcur[tn] = bnxt[tn];
    }

    // ---- epilogue: +bias, min over co, cross-lane min, tanh(tanh) ----
    float bvv[4];
#pragma unroll
    for (int tn = 0; tn < 4; ++tn)
        bvv[tn] = bias[wn * 64 + tn * 16 + r16];

#pragma unroll
    for (int tm = 0; tm < 8; ++tm) {
#pragma unroll
        for (int r = 0; r < 4; ++r) {
            // C/D: row(m) = quad*4 + r, col(co) = r16
            float v = acc[tm][0][r] + bvv[0];
            v = fminf(v, acc[tm][1][r] + bvv[1]);
            v = fminf(v, acc[tm][2][r] + bvv[2]);
            v = fminf(v, acc[tm][3][r] + bvv[3]);
            v = fminf(v, __shfl_xor(v, 1, 64));
            v = fminf(v, __shfl_xor(v, 2, 64));
            v = fminf(v, __shfl_xor(v, 4, 64));
            v = fminf(v, __shfl_xor(v, 8, 64));
            if (r16 == 0)
                red[wn][wm * 128 + tm * 16 + quad * 4 + r] = v;
        }
    }
    __syncthreads();

    {
        const int r  = tid >> 7;       // out-row within pair
        const int wo = tid & 127;
        if (wo < 126) {
            float v = fminf(red[0][tid], red[1][tid]);
            v = tanhf(tanhf(v));
            out[((size_t)n * 126 + ho0 + r) * 126 + wo] = v;
        }
    }
}

// ---------------- fallback (proven r2 path): register-staged f32 ----------
__global__ void w2_prepass(const float* __restrict__ w, ushort_t* __restrict__ w2) {
    int idx = blockIdx.x * 256 + threadIdx.x;  // 73728
    int rd  = idx >> 12;
    int rem = idx & 4095;
    int co  = rem >> 5;
    int c32 = rem & 31;
    int khw = rd >> 1, half = rd & 1;
    int ci  = half * 32 + c32;
    w2[idx] = (ushort_t)(rne_u(w[co * 576 + ci * 9 + khw]) >> 16);
}

template<bool USE_W2>
__global__ __launch_bounds__(512, 4)
void conv_min_tanh_kernel(const float* __restrict__ x,
                          const float* __restrict__ w,
                          const ushort_t* __restrict__ w2,
                          const float* __restrict__ bias,
                          float* __restrict__ out)
{
    __shared__ __align__(16) ushort_t T[4 * TSZ];
    __shared__ __align__(16) float red[2][256];

    const int tid  = threadIdx.x;
    const int bid0 = blockIdx.x;
    const int bid  = (bid0 & 7) * 252 + (bid0 >> 3);
    const int n    = bid / 63;
    const int ho0  = (bid - n * 63) * 2;

    const int tx = tid & 31;
    const int ty = tid >> 5;

    const int lane = tid & 63;
    const int wid  = tid >> 6;
    const int wm   = wid >> 1;
    const int wn   = wid & 1;
    const int r16  = lane & 15;
    const int quad = lane >> 4;

    const float* xbase = x + ((size_t)n << 20) + (size_t)ho0 * 128;

    auto load_row = [&](floatx4 (&dv)[4], const int s) {
#pragma unroll
        for (int j = 0; j < 4; ++j)
            dv[j] = *reinterpret_cast<const floatx4*>(
                xbase + (size_t)(ty * 4 + j) * 16384 + s * 128 + tx * 4);
    };
    auto conv_row = [&](floatx4 (&dv)[4], const int s) {
#pragma unroll
        for (int i = 0; i < 4; ++i) {
            uint2 u;
            u.x = pk2(dv[0][i], dv[1][i]);
            u.y = pk2(dv[2][i], dv[3][i]);
            const int c   = tx * 4 + i;
            const int swz = (ty >> 1) ^ ((c >> 3) & 7);
            *reinterpret_cast<uint2*>(&T[s * TSZ + c * RSTR + swz * 8 + (ty & 1) * 4]) = u;
        }
    };

    floatx4 dva[4], dvb[4];
    load_row(dva, 0);
    load_row(dvb, 1);

    for (int idx = tid; idx < 576; idx += 512) {
        int s = idx / 144, o = idx - s * 144;
        reinterpret_cast<uint_t*>(T)[s * (TSZ / 2) + (128 * RSTR) / 2 + o] = 0u;
    }

    conv_row(dva, 0);
    load_row(dva, 2);
    conv_row(dvb, 1);
    load_row(dvb, 3);
    conv_row(dva, 2);
    conv_row(dvb, 3);

    floatx4 acc[4][4];
#pragma unroll
    for (int i = 0; i < 4; ++i)
#pragma unroll
        for (int j = 0; j < 4; ++j)
            acc[i][j] = (floatx4){0.f, 0.f, 0.f, 0.f};

    const ushort_t* w2base = w2 + (size_t)(wn * 64 + r16) * 32 + quad * 8;
    const float*    wbase  = w + (size_t)(wn * 64 + r16) * 576;

    __syncthreads();

#pragma unroll
    for (int rd = 0; rd < 18; ++rd) {
        const int khw  = rd >> 1;
        const int kh   = khw / 3;
        const int kw   = khw - kh * 3;
        const int half = rd & 1;

        short8_t bfr[4];
        if (USE_W2) {
            const ushort_t* bb = w2base + rd * 4096;
#pragma unroll
            for (int t4 = 0; t4 < 4; ++t4)
                bfr[t4] = *reinterpret_cast<const short8_t*>(bb + t4 * 512);
        } else {
#pragma unroll
            for (int t4 = 0; t4 < 4; ++t4) {
                const float* wp = wbase + (size_t)t4 * (16 * 576)
                                + (size_t)(half * 32 + quad * 8) * 9 + khw;
                short8_t b;
#pragma unroll
                for (int q = 0; q < 4; ++q) {
                    uint_t u = pk2(wp[(2 * q) * 9], wp[(2 * q + 1) * 9]);
                    b[2 * q]     = (short)(u & 0xffffu);
                    b[2 * q + 1] = (short)(u >> 16);
                }
                bfr[t4] = b;
            }
        }

        short8_t afr[4];
#pragma unroll
        for (int t4 = 0; t4 < 4; ++t4) {
            const int m  = wm * 64 + t4 * 16 + r16;
            const int s  = (m >> 7) + kh;
            const int c  = (m & 127) + kw;
            const int sw = (half * 4 + quad) ^ ((c >> 3) & 7);
            afr[t4] = *reinterpret_cast<const short8_t*>(&T[s * TSZ + c * RSTR + sw * 8]);
        }
#pragma unroll
        for (int tm = 0; tm < 4; ++tm)
#pragma unroll
            for (int tn = 0; tn < 4; ++tn)
                acc[tm][tn] = __builtin_amdgcn_mfma_f32_16x16x32_bf16(
                    afr[tm], bfr[tn], acc[tm][tn], 0, 0, 0);
    }

    float bvv[4];
#pragma unroll
    for (int tn = 0; tn < 4; ++tn)
        bvv[tn] = bias[wn * 64 + tn * 16 + r16];

#pragma unroll
    for (int tm = 0; tm < 4; ++tm) {
#pragma unroll
        for (int r = 0; r < 4; ++r) {
            float v = acc[tm][0][r] + bvv[0];
            v = fminf(v, acc[tm][1][r] + bvv[1]);
            v = fminf(v, acc[tm][2][r] + bvv[2]);
            v = fminf(v, acc[tm][3][r] + bvv[3]);
            v = fminf(v, __shfl_xor(v, 1, 64));
            v = fminf(v, __shfl_xor(v, 2, 64));
            v = fminf(v, __shfl_xor(v, 4, 64));
            v = fminf(v, __shfl_xor(v, 8, 64));
            if (r16 == 0)
                red[wn][wm * 64 + tm * 16 + quad * 4 + r] = v;
        }
    }
    __syncthreads();

    if (tid < 256) {
        const int r  = tid >> 7;
        const int wo = tid & 127;
        if (wo < 126) {
            float v = fminf(red[0][tid], red[1][tid]);
            v = tanhf(tanhf(v));
            out[((size_t)n * 126 + ho0 + r) * 126 + wo] = v;
        }
    }
}

extern "C" void kernel_launch(void* const* d_in, const int* in_sizes, int n_in,
                              void* d_out, int out_size, void* d_ws, size_t ws_size,
                              hipStream_t stream) {
    const float* x    = (const float*)d_in[0];   // [32,64,128,128] f32
    const float* w    = (const float*)d_in[1];   // [128,64,3,3] f32
    const float* bias = (const float*)d_in[2];   // [128] f32
    float* out = (float*)d_out;                  // [32,1,126,126] f32

    const size_t X2B = (size_t)32 * 128 * 128 * 64 * 2;   // 67,108,864 B
    const size_t W2B = (size_t)73728 * 2;                 // 147,456 B

    if (ws_size >= X2B + W2B) {
        ushort_t* x2 = (ushort_t*)d_ws;
        ushort_t* w2 = (ushort_t*)((char*)d_ws + X2B);
        prepass_fused<<<dim3(4096 + 288), dim3(256), 0, stream>>>(x, w, x2, w2);
        conv_v8<<<dim3(2016), dim3(256), 0, stream>>>(x2, w2, bias, out);
    } else if (ws_size >= W2B) {
        ushort_t* w2 = (ushort_t*)d_ws;
        w2_prepass<<<dim3(288), dim3(256), 0, stream>>>(w, w2);
        conv_min_tanh_kernel<true><<<dim3(2016), dim3(512), 0, stream>>>(x, w, w2, bias, out);
    } else {
        conv_min_tanh_kernel<false><<<dim3(2016), dim3(512), 0, stream>>>(x, w, nullptr, bias, out);
    }
}